// Round 1
// baseline (298.606 us; speedup 1.0000x reference)
//
#include <hip/hip_runtime.h>
#include <hip/hip_bf16.h>

#define B_   64
#define T_   4096
#define K_   67
#define F_   134     // 2K input features
#define FP_  160     // padded to 5 K-tiles of 32
#define D_   256
#define C_   7
#define THR_ 0.1f
#define EPS_ 1e-5f

typedef __bf16 bf16x8 __attribute__((ext_vector_type(8)));
typedef float  f32x4  __attribute__((ext_vector_type(4)));

// ws layout:
//   [0, 65536)            pooled  f32 [64][256]   (memset to 0 each launch)
//   [65536, 65536+81920)  W1bf    bf16 [256][160] (d-major, f contiguous, padded)

__device__ __forceinline__ int a_idx(int t, int f) {
    // MFMA-A-fragment-ready LDS layout for a 32t x 160f tile:
    // region (mtile*5+ktile) of 512 elems; within: lane*8 + j,
    // lane = quad*16 + (t&15), quad = (f&31)>>3, j = f&7.
    return (((t >> 4) * 5 + (f >> 5)) * 512) +
           ((((f >> 3) & 3) * 16 + (t & 15)) * 8) + (f & 7);
}

__device__ __forceinline__ int get_len(const int* L, int b) {
    // defensive: if harness stored int64 (odd words are zero since 1<=len<=4096),
    // stride by 2. For int32, L[1] in [1,4096] != 0.
    return (L[1] == 0) ? L[2 * b] : L[b];
}

__global__ void convert_w1(const float* __restrict__ W1, __bf16* __restrict__ W1bf) {
    int idx = blockIdx.x * 256 + threadIdx.x;     // 256*160 = 40960 elems
    if (idx >= D_ * FP_) return;
    int d = idx / FP_, f = idx % FP_;
    float v = (f < F_) ? W1[f * D_ + d] : 0.f;
    W1bf[idx] = (__bf16)v;
}

__global__ __launch_bounds__(256, 2)
void fused_mlp_pool(const float* __restrict__ body,
                    const float* __restrict__ hr,
                    const float* __restrict__ hl,
                    const int*   __restrict__ length,
                    const float* __restrict__ b1,
                    const __bf16* __restrict__ W1bf,
                    float* __restrict__ pooled)
{
    const int b = blockIdx.y;
    const int len = get_len(length, b);
    const int tbase = blockIdx.x * 256;           // 256 timesteps per block
    if (tbase >= len) return;                     // length skip (~2x traffic cut)

    __shared__ __align__(16) __bf16 As[2 * 5 * 512];   // 10 KiB

    const int tid  = threadIdx.x;
    const int wave = tid >> 6;
    const int lane = tid & 63;
    const int quad = lane >> 4;
    const int l16  = lane & 15;
    const int dbase = wave * 64;                  // each wave owns 64 d's

    // zero the K-padding region f in [134,160) once (never overwritten)
    for (int i = tid; i < 32 * 13; i += 256) {
        int t = i / 13;
        int f = 134 + 2 * (i % 13);
        int idx = a_idx(t, f);
        *(unsigned int*)((unsigned short*)As + idx) = 0u;
    }

    // hoist all B fragments: W1bf row d = dbase + n*16 + l16, k = kt*32 + quad*8 + j
    bf16x8 bfrag[4][5];
    float  b1v[4];
#pragma unroll
    for (int n = 0; n < 4; n++) {
        int d = dbase + n * 16 + l16;
        const __bf16* p = W1bf + d * FP_ + quad * 8;
#pragma unroll
        for (int kt = 0; kt < 5; kt++)
            bfrag[n][kt] = *(const bf16x8*)(p + kt * 32);
        b1v[n] = b1[d];
    }

    float runmax[4] = {0.f, 0.f, 0.f, 0.f};

    const int ts = tid >> 3;      // local t row 0..31
    const int k0 = tid & 7;       // keypoint start
    const long rowb = (long)b * T_;

    for (int c = 0; c < 8; c++) {
        int t0 = tbase + c * 32;
        if (t0 >= len) break;
        int tg = t0 + ts;

        // --- stage gated pos -> LDS (bf16, frag-ready layout) ---
        for (int k = k0; k < K_; k += 8) {
            const float* src;
            if (k < 25)      src = body + (rowb + tg) * 75 + k * 3;
            else if (k < 46) src = hr   + (rowb + tg) * 63 + (k - 25) * 3;
            else             src = hl   + (rowb + tg) * 63 + (k - 46) * 3;
            float x = src[0], y = src[1], cf = src[2];
            if (!(cf > THR_)) { x = 0.f; y = 0.f; }
            unsigned short ux = __builtin_bit_cast(unsigned short, (__bf16)x);
            unsigned short uy = __builtin_bit_cast(unsigned short, (__bf16)y);
            int idx = a_idx(ts, 2 * k);   // f even -> pair stays in one octet
            *(unsigned int*)((unsigned short*)As + idx) =
                (unsigned int)ux | ((unsigned int)uy << 16);
        }
        __syncthreads();

        // --- MFMA: 32t x 256d, K = 160 ---
        f32x4 acc[2][4];
#pragma unroll
        for (int m = 0; m < 2; m++)
#pragma unroll
            for (int n = 0; n < 4; n++)
                acc[m][n] = (f32x4){0.f, 0.f, 0.f, 0.f};

#pragma unroll
        for (int kt = 0; kt < 5; kt++) {
            bf16x8 a0 = *(const bf16x8*)(As + (0 * 5 + kt) * 512 + lane * 8);
            bf16x8 a1 = *(const bf16x8*)(As + (1 * 5 + kt) * 512 + lane * 8);
#pragma unroll
            for (int n = 0; n < 4; n++) {
                acc[0][n] = __builtin_amdgcn_mfma_f32_16x16x32_bf16(a0, bfrag[n][kt], acc[0][n], 0, 0, 0);
                acc[1][n] = __builtin_amdgcn_mfma_f32_16x16x32_bf16(a1, bfrag[n][kt], acc[1][n], 0, 0, 0);
            }
        }

        // --- epilogue: bias + relu + validity clamp + running max ---
#pragma unroll
        for (int m = 0; m < 2; m++) {
            int trow0 = t0 + m * 16 + quad * 4;   // D row = quad*4 + reg
#pragma unroll
            for (int r = 0; r < 4; r++) {
                bool valid = (trow0 + r) < len;
#pragma unroll
                for (int n = 0; n < 4; n++) {
                    float v = acc[m][n][r] + b1v[n];
                    v = (v > 0.f) ? v : 0.f;      // forces +0, never -0
                    runmax[n] = (valid && v > runmax[n]) ? v : runmax[n];
                }
            }
        }
        __syncthreads();   // LDS reuse barrier before next stage
    }

    // reduce across row-quads, then one atomicMax per lane
#pragma unroll
    for (int n = 0; n < 4; n++) {
        float r = runmax[n];
        r = fmaxf(r, __shfl_xor(r, 16, 64));
        r = fmaxf(r, __shfl_xor(r, 32, 64));
        if (quad == n) {
            atomicMax((unsigned int*)(pooled + b * D_ + dbase + n * 16 + l16),
                      __float_as_uint(r));   // all values >= +0
        }
    }
}

__global__ void bn_classifier(const float* __restrict__ pooled,
                              const float* __restrict__ gamma,
                              const float* __restrict__ beta,
                              const float* __restrict__ Wc,
                              const float* __restrict__ bc,
                              float* __restrict__ out)
{
    __shared__ float scale_s[D_], shift_s[D_];
    int tid = threadIdx.x;   // == d
    float s = 0.f, ss = 0.f;
    for (int b = 0; b < B_; b++) {
        float v = pooled[b * D_ + tid];
        s += v; ss += v * v;
    }
    float mean = s * (1.f / B_);
    float var  = ss * (1.f / B_) - mean * mean;
    var = fmaxf(var, 0.f);
    float sc = gamma[tid] * rsqrtf(var + EPS_);
    scale_s[tid] = sc;
    shift_s[tid] = beta[tid] - mean * sc;
    __syncthreads();

    for (int o = tid; o < B_ * C_; o += 256) {
        int b = o / C_, c = o % C_;
        float acc = bc[c];
        for (int d = 0; d < D_; d++)
            acc += (pooled[b * D_ + d] * scale_s[d] + shift_s[d]) * Wc[d * C_ + c];
        out[o] = acc;
    }
}

extern "C" void kernel_launch(void* const* d_in, const int* in_sizes, int n_in,
                              void* d_out, int out_size, void* d_ws, size_t ws_size,
                              hipStream_t stream) {
    const float* body   = (const float*)d_in[0];
    const float* hr     = (const float*)d_in[1];
    const float* hl     = (const float*)d_in[2];
    const int*   length = (const int*)  d_in[3];
    const float* W1     = (const float*)d_in[4];
    const float* b1     = (const float*)d_in[5];
    const float* gamma  = (const float*)d_in[6];
    const float* beta   = (const float*)d_in[7];
    const float* Wc     = (const float*)d_in[8];
    const float* bc     = (const float*)d_in[9];
    float* out = (float*)d_out;

    float*  pooled = (float*)d_ws;
    __bf16* W1bf   = (__bf16*)((char*)d_ws + 65536);

    hipMemsetAsync(d_ws, 0, 65536, stream);                    // pooled = 0 (relu >= 0)
    convert_w1<<<dim3(160), dim3(256), 0, stream>>>(W1, W1bf);
    fused_mlp_pool<<<dim3(16, B_), dim3(256), 0, stream>>>(body, hr, hl, length, b1, W1bf, pooled);
    bn_classifier<<<dim3(1), dim3(256), 0, stream>>>(pooled, gamma, beta, Wc, bc, out);
}

// Round 2
// 284.354 us; speedup vs baseline: 1.0501x; 1.0501x over previous
//
#include <hip/hip_runtime.h>
#include <hip/hip_bf16.h>

#define B_   64
#define T_   4096
#define K_   67
#define F_   134     // 2K input features
#define FP_  160     // padded to 5 K-tiles of 32
#define D_   256
#define C_   7
#define THR_ 0.1f
#define EPS_ 1e-5f

typedef __bf16 bf16x8 __attribute__((ext_vector_type(8)));
typedef float  f32x4  __attribute__((ext_vector_type(4)));

// ws layout:
//   [0, 65536)            pooled  f32 [64][256]   (memset to 0 each launch)
//   [65536, 65536+81920)  W1bf    bf16 [256][160] (d-major, f contiguous, padded)

__device__ __forceinline__ int a_idx(int t, int f) {
    // MFMA-A-fragment-ready LDS layout for a 32t x 160f tile:
    // region (mtile*5+ktile) of 512 elems; within: lane*8 + j,
    // lane = quad*16 + (t&15), quad = (f&31)>>3, j = f&7.
    return (((t >> 4) * 5 + (f >> 5)) * 512) +
           ((((f >> 3) & 3) * 16 + (t & 15)) * 8) + (f & 7);
}

__device__ __forceinline__ int get_len(const int* L, int b) {
    // defensive: harness may store int64 (odd words zero since 1<=len<=4096)
    return (L[1] == 0) ? L[2 * b] : L[b];
}

__global__ void convert_w1(const float* __restrict__ W1, __bf16* __restrict__ W1bf) {
    int idx = blockIdx.x * 256 + threadIdx.x;     // 160*256 = 40960 threads
    if (idx < F_ * D_) {
        // coalesced read: consecutive threads -> consecutive d within row f
        int f = idx >> 8, d = idx & 255;
        W1bf[d * FP_ + f] = (__bf16)W1[idx];
    } else if (idx < D_ * FP_) {
        int i2 = idx - F_ * D_;                   // 256 d x 26 pad f
        int d = i2 / 26, f = F_ + i2 % 26;
        W1bf[d * FP_ + f] = (__bf16)0.f;
    }
}

__device__ __forceinline__ void stage_triple(const float* p, int t, int kglob,
                                             __bf16* As) {
    float x = p[0], y = p[1], cf = p[2];
    if (!(cf > THR_)) { x = 0.f; y = 0.f; }
    unsigned short ux = __builtin_bit_cast(unsigned short, (__bf16)x);
    unsigned short uy = __builtin_bit_cast(unsigned short, (__bf16)y);
    int idx = a_idx(t, 2 * kglob);   // f even -> pair stays in one dword
    *(unsigned int*)((unsigned short*)As + idx) =
        (unsigned int)ux | ((unsigned int)uy << 16);
}

__global__ __launch_bounds__(256, 3)
void fused_mlp_pool(const float* __restrict__ body,
                    const float* __restrict__ hr,
                    const float* __restrict__ hl,
                    const int*   __restrict__ length,
                    const float* __restrict__ b1,
                    const __bf16* __restrict__ W1bf,
                    float* __restrict__ pooled)
{
    const int b = blockIdx.y;
    const int len = get_len(length, b);
    const int cbase = blockIdx.x * 128;           // 4 tiles of 32 t per block
    if (cbase >= len) return;

    __shared__ __align__(16) __bf16 As[2 * 5 * 512];   // 10 KiB

    const int tid  = threadIdx.x;
    const int wave = tid >> 6;
    const int lane = tid & 63;
    const int quad = lane >> 4;
    const int l16  = lane & 15;
    const int dbase = wave * 64;                  // each wave owns 64 d's

    // zero the K-padding region f in [134,160) once (never overwritten)
    for (int i = tid; i < 32 * 13; i += 256) {
        int t = i / 13;
        int f = 134 + 2 * (i % 13);
        *(unsigned int*)((unsigned short*)As + a_idx(t, f)) = 0u;
    }

    // hoist all B fragments (held in regs for all 4 tiles):
    // W1bf row d = dbase + n*16 + l16, k = kt*32 + quad*8 + j
    bf16x8 bfrag[4][5];
    float  b1v[4];
#pragma unroll
    for (int n = 0; n < 4; n++) {
        int d = dbase + n * 16 + l16;
        const __bf16* p = W1bf + d * FP_ + quad * 8;
#pragma unroll
        for (int kt = 0; kt < 5; kt++)
            bfrag[n][kt] = *(const bf16x8*)(p + kt * 32);
        b1v[n] = b1[d];
    }

    float runmax[4] = {0.f, 0.f, 0.f, 0.f};
    const long rowb = (long)b * T_;

    for (int c = 0; c < 4; c++) {
        const int t0 = cbase + c * 32;
        if (t0 >= len) break;                     // block-uniform
        if (c) __syncthreads();                   // protect LDS vs prev MFMA reads

        // --- dense coalesced staging: consecutive threads load consecutive
        //     12-B keypoint triples ---
        const float* bodyt = body + (rowb + t0) * 75;
        for (int j = tid; j < 32 * 25; j += 256) {        // body: 800 triples
            int t = j / 25, k = j - t * 25;
            stage_triple(bodyt + t * 75 + k * 3, t, k, As);
        }
        const float* hrt = hr + (rowb + t0) * 63;
        for (int j = tid; j < 32 * 21; j += 256) {        // right hand: 672
            int t = j / 21, k = j - t * 21;
            stage_triple(hrt + t * 63 + k * 3, t, 25 + k, As);
        }
        const float* hlt = hl + (rowb + t0) * 63;
        for (int j = tid; j < 32 * 21; j += 256) {        // left hand: 672
            int t = j / 21, k = j - t * 21;
            stage_triple(hlt + t * 63 + k * 3, t, 46 + k, As);
        }
        __syncthreads();

        // --- MFMA: 32t x 256d, K = 160 ---
        f32x4 acc[2][4];
#pragma unroll
        for (int m = 0; m < 2; m++)
#pragma unroll
            for (int n = 0; n < 4; n++)
                acc[m][n] = (f32x4){0.f, 0.f, 0.f, 0.f};

#pragma unroll
        for (int kt = 0; kt < 5; kt++) {
            bf16x8 a0 = *(const bf16x8*)(As + (0 * 5 + kt) * 512 + lane * 8);
            bf16x8 a1 = *(const bf16x8*)(As + (1 * 5 + kt) * 512 + lane * 8);
#pragma unroll
            for (int n = 0; n < 4; n++) {
                acc[0][n] = __builtin_amdgcn_mfma_f32_16x16x32_bf16(a0, bfrag[n][kt], acc[0][n], 0, 0, 0);
                acc[1][n] = __builtin_amdgcn_mfma_f32_16x16x32_bf16(a1, bfrag[n][kt], acc[1][n], 0, 0, 0);
            }
        }

        // --- epilogue: bias + relu + validity clamp + running max ---
#pragma unroll
        for (int m = 0; m < 2; m++) {
            int trow0 = t0 + m * 16 + quad * 4;   // T row = quad*4 + reg
#pragma unroll
            for (int r = 0; r < 4; r++) {
                bool valid = (trow0 + r) < len;
#pragma unroll
                for (int n = 0; n < 4; n++) {
                    float v = acc[m][n][r] + b1v[n];
                    v = (v > 0.f) ? v : 0.f;      // forces +0, never -0
                    runmax[n] = (valid && v > runmax[n]) ? v : runmax[n];
                }
            }
        }
    }

    // reduce across row-quads, then one atomicMax per thread (same b all tiles)
#pragma unroll
    for (int n = 0; n < 4; n++) {
        float r = runmax[n];
        r = fmaxf(r, __shfl_xor(r, 16, 64));
        r = fmaxf(r, __shfl_xor(r, 32, 64));
        if (quad == n) {
            atomicMax((unsigned int*)(pooled + b * D_ + dbase + n * 16 + l16),
                      __float_as_uint(r));   // all values >= +0
        }
    }
}

__global__ void bn_classifier(const float* __restrict__ pooled,
                              const float* __restrict__ gamma,
                              const float* __restrict__ beta,
                              const float* __restrict__ Wc,
                              const float* __restrict__ bc,
                              float* __restrict__ out)
{
    __shared__ float scale_s[D_], shift_s[D_];
    const int tid = threadIdx.x;   // == d for stats
    float s = 0.f, ss = 0.f;
#pragma unroll 8
    for (int b = 0; b < B_; b++) {
        float v = pooled[b * D_ + tid];   // coalesced
        s += v; ss += v * v;
    }
    float mean = s * (1.f / B_);
    float var  = ss * (1.f / B_) - mean * mean;
    var = fmaxf(var, 0.f);
    float sc = gamma[tid] * rsqrtf(var + EPS_);
    scale_s[tid] = sc;
    shift_s[tid] = beta[tid] - mean * sc;

    // per-lane classifier weights: rows ln*4 .. ln*4+3 of Wc (dense read, L2)
    const int wv = tid >> 6, ln = tid & 63;
    float wcr[4][C_];
#pragma unroll
    for (int j = 0; j < 4; j++)
#pragma unroll
        for (int c = 0; c < C_; c++)
            wcr[j][c] = Wc[(ln * 4 + j) * C_ + c];
    __syncthreads();

    // wave wv handles batches [wv*16, wv*16+16)
    for (int b = wv * 16; b < wv * 16 + 16; b++) {
        float4 v = *(const float4*)(pooled + b * D_ + ln * 4);   // coalesced
        float q[4];
        q[0] = v.x * scale_s[ln * 4 + 0] + shift_s[ln * 4 + 0];
        q[1] = v.y * scale_s[ln * 4 + 1] + shift_s[ln * 4 + 1];
        q[2] = v.z * scale_s[ln * 4 + 2] + shift_s[ln * 4 + 2];
        q[3] = v.w * scale_s[ln * 4 + 3] + shift_s[ln * 4 + 3];
        float p[C_];
#pragma unroll
        for (int c = 0; c < C_; c++) p[c] = 0.f;
#pragma unroll
        for (int j = 0; j < 4; j++)
#pragma unroll
            for (int c = 0; c < C_; c++)
                p[c] += q[j] * wcr[j][c];
#pragma unroll
        for (int c = 0; c < C_; c++) {
#pragma unroll
            for (int off = 1; off < 64; off <<= 1)
                p[c] += __shfl_xor(p[c], off, 64);
        }
        if (ln == 0) {
#pragma unroll
            for (int c = 0; c < C_; c++)
                out[b * C_ + c] = p[c] + bc[c];
        }
    }
}

extern "C" void kernel_launch(void* const* d_in, const int* in_sizes, int n_in,
                              void* d_out, int out_size, void* d_ws, size_t ws_size,
                              hipStream_t stream) {
    const float* body   = (const float*)d_in[0];
    const float* hr     = (const float*)d_in[1];
    const float* hl     = (const float*)d_in[2];
    const int*   length = (const int*)  d_in[3];
    const float* W1     = (const float*)d_in[4];
    const float* b1     = (const float*)d_in[5];
    const float* gamma  = (const float*)d_in[6];
    const float* beta   = (const float*)d_in[7];
    const float* Wc     = (const float*)d_in[8];
    const float* bc     = (const float*)d_in[9];
    float* out = (float*)d_out;

    float*  pooled = (float*)d_ws;
    __bf16* W1bf   = (__bf16*)((char*)d_ws + 65536);

    hipMemsetAsync(d_ws, 0, 65536, stream);                    // pooled = 0 (relu >= 0)
    convert_w1<<<dim3(160), dim3(256), 0, stream>>>(W1, W1bf);
    fused_mlp_pool<<<dim3(32, B_), dim3(256), 0, stream>>>(body, hr, hl, length, b1, W1bf, pooled);
    bn_classifier<<<dim3(1), dim3(256), 0, stream>>>(pooled, gamma, beta, Wc, bc, out);
}

// Round 3
// 256.447 us; speedup vs baseline: 1.1644x; 1.1088x over previous
//
#include <hip/hip_runtime.h>
#include <hip/hip_bf16.h>

#define B_   64
#define T_   4096
#define K_   67
#define F_   134     // 2K input features
#define FP_  160     // padded to 5 K-tiles of 32
#define D_   256
#define C_   7
#define THR_ 0.1f
#define EPS_ 1e-5f

typedef __bf16 bf16x8 __attribute__((ext_vector_type(8)));
typedef float  f32x4  __attribute__((ext_vector_type(4)));

// ws layout:
//   [0, 65536)            pooled  f32 [64][256]   (memset to 0 each launch)
//   [65536, 65536+81920)  W1bf    bf16 [256][160] (d-major, f contiguous, padded)

__device__ __forceinline__ int a_idx(int t, int f) {
    // MFMA-A-fragment-ready LDS layout for a 16t x 32f sub-tile grid:
    // region (mtile*5+ktile) of 512 elems; within: lane*8 + j,
    // lane = quad*16 + (t&15), quad = (f&31)>>3, j = f&7.
    return (((t >> 4) * 5 + (f >> 5)) * 512) +
           ((((f >> 3) & 3) * 16 + (t & 15)) * 8) + (f & 7);
}

__device__ __forceinline__ int get_len(const int* L, int b) {
    // defensive: harness may store int64 (odd words zero since 1<=len<=4096)
    return (L[1] == 0) ? L[2 * b] : L[b];
}

__global__ void convert_w1(const float* __restrict__ W1, __bf16* __restrict__ W1bf) {
    int idx = blockIdx.x * 256 + threadIdx.x;     // 160 blocks x 256
    if (idx >= D_ * FP_) return;
    int d = idx / FP_, f = idx - d * FP_;         // consecutive tid -> consecutive f
    float v = (f < F_) ? W1[f * D_ + d] : 0.f;    // reads scattered (L2), writes dense
    W1bf[idx] = (__bf16)v;
}

__device__ __forceinline__ void stage_triple(const float* p, int t, int kglob,
                                             __bf16* As) {
    float x = p[0], y = p[1], cf = p[2];
    if (!(cf > THR_)) { x = 0.f; y = 0.f; }
    unsigned short ux = __builtin_bit_cast(unsigned short, (__bf16)x);
    unsigned short uy = __builtin_bit_cast(unsigned short, (__bf16)y);
    int idx = a_idx(t, 2 * kglob);   // f even -> pair stays in one dword
    *(unsigned int*)((unsigned short*)As + idx) =
        (unsigned int)ux | ((unsigned int)uy << 16);
}

// One 64-timestep tile per block. Single barrier, no inter-tile loop.
__global__ __launch_bounds__(256, 2)
void fused_mlp_pool(const float* __restrict__ body,
                    const float* __restrict__ hr,
                    const float* __restrict__ hl,
                    const int*   __restrict__ length,
                    const float* __restrict__ b1,
                    const __bf16* __restrict__ W1bf,
                    float* __restrict__ pooled)
{
    const int b = blockIdx.y;
    const int len = get_len(length, b);
    const int t0 = blockIdx.x * 64;               // one 64-t tile
    if (t0 >= len) return;

    __shared__ __align__(16) __bf16 As[4 * 5 * 512];   // 20 KiB: 64t x 160f

    const int tid  = threadIdx.x;
    const int wave = tid >> 6;
    const int lane = tid & 63;
    const int quad = lane >> 4;
    const int l16  = lane & 15;
    const int dbase = wave * 64;                  // each wave owns 64 d's

    // issue B-fragment loads first (independent; overlap with staging)
    // W1bf row d = dbase + n*16 + l16, k = kt*32 + quad*8 + j
    bf16x8 bfrag[4][5];
    float  b1v[4];
#pragma unroll
    for (int n = 0; n < 4; n++) {
        int d = dbase + n * 16 + l16;
        const __bf16* p = W1bf + d * FP_ + quad * 8;
#pragma unroll
        for (int kt = 0; kt < 5; kt++)
            bfrag[n][kt] = *(const bf16x8*)(p + kt * 32);
        b1v[n] = b1[d];
    }

    // zero the K-padding region f in [134,160), t in [0,64)
    for (int i = tid; i < 64 * 13; i += 256) {
        int t = i / 13;
        int f = 134 + 2 * (i % 13);
        *(unsigned int*)((unsigned short*)As + a_idx(t, f)) = 0u;
    }

    // --- dense coalesced staging: consecutive threads load consecutive
    //     12-B keypoint triples ---
    const long rowb = (long)b * T_;
    const float* bodyt = body + (rowb + t0) * 75;
    for (int j = tid; j < 64 * 25; j += 256) {        // body: 1600 triples
        int t = j / 25, k = j - t * 25;
        stage_triple(bodyt + t * 75 + k * 3, t, k, As);
    }
    const float* hrt = hr + (rowb + t0) * 63;
    for (int j = tid; j < 64 * 21; j += 256) {        // right hand: 1344
        int t = j / 21, k = j - t * 21;
        stage_triple(hrt + t * 63 + k * 3, t, 25 + k, As);
    }
    const float* hlt = hl + (rowb + t0) * 63;
    for (int j = tid; j < 64 * 21; j += 256) {        // left hand: 1344
        int t = j / 21, k = j - t * 21;
        stage_triple(hlt + t * 63 + k * 3, t, 46 + k, As);
    }
    __syncthreads();                                   // the ONLY barrier

    // --- MFMA: 64t x 256d, K = 160 ---
    f32x4 acc[4][4];
#pragma unroll
    for (int m = 0; m < 4; m++)
#pragma unroll
        for (int n = 0; n < 4; n++)
            acc[m][n] = (f32x4){0.f, 0.f, 0.f, 0.f};

#pragma unroll
    for (int kt = 0; kt < 5; kt++) {
#pragma unroll
        for (int m = 0; m < 4; m++) {
            bf16x8 a = *(const bf16x8*)(As + (m * 5 + kt) * 512 + lane * 8);
#pragma unroll
            for (int n = 0; n < 4; n++)
                acc[m][n] = __builtin_amdgcn_mfma_f32_16x16x32_bf16(a, bfrag[n][kt], acc[m][n], 0, 0, 0);
        }
    }

    // --- epilogue: bias + relu + validity clamp + running max ---
    float runmax[4] = {0.f, 0.f, 0.f, 0.f};
#pragma unroll
    for (int m = 0; m < 4; m++) {
        int trow0 = t0 + m * 16 + quad * 4;   // T row = quad*4 + reg
#pragma unroll
        for (int r = 0; r < 4; r++) {
            bool valid = (trow0 + r) < len;
#pragma unroll
            for (int n = 0; n < 4; n++) {
                float v = acc[m][n][r] + b1v[n];
                v = (v > 0.f) ? v : 0.f;      // forces +0, never -0
                runmax[n] = (valid && v > runmax[n]) ? v : runmax[n];
            }
        }
    }

    // reduce across row-quads, then one atomicMax per thread
#pragma unroll
    for (int n = 0; n < 4; n++) {
        float r = runmax[n];
        r = fmaxf(r, __shfl_xor(r, 16, 64));
        r = fmaxf(r, __shfl_xor(r, 32, 64));
        if (quad == n) {
            atomicMax((unsigned int*)(pooled + b * D_ + dbase + n * 16 + l16),
                      __float_as_uint(r));   // all values >= +0
        }
    }
}

__global__ void bn_classifier(const float* __restrict__ pooled,
                              const float* __restrict__ gamma,
                              const float* __restrict__ beta,
                              const float* __restrict__ Wc,
                              const float* __restrict__ bc,
                              float* __restrict__ out)
{
    __shared__ float scale_s[D_], shift_s[D_];
    const int tid = threadIdx.x;   // == d for stats
    float s = 0.f, ss = 0.f;
#pragma unroll 8
    for (int b = 0; b < B_; b++) {
        float v = pooled[b * D_ + tid];   // coalesced
        s += v; ss += v * v;
    }
    float mean = s * (1.f / B_);
    float var  = ss * (1.f / B_) - mean * mean;
    var = fmaxf(var, 0.f);
    float sc = gamma[tid] * rsqrtf(var + EPS_);
    scale_s[tid] = sc;
    shift_s[tid] = beta[tid] - mean * sc;

    // per-lane classifier weights: rows ln*4 .. ln*4+3 of Wc
    const int wv = tid >> 6, ln = tid & 63;
    float wcr[4][C_];
#pragma unroll
    for (int j = 0; j < 4; j++)
#pragma unroll
        for (int c = 0; c < C_; c++)
            wcr[j][c] = Wc[(ln * 4 + j) * C_ + c];
    __syncthreads();

    // wave wv handles batches [wv*16, wv*16+16)
    for (int b = wv * 16; b < wv * 16 + 16; b++) {
        float4 v = *(const float4*)(pooled + b * D_ + ln * 4);   // coalesced
        float q[4];
        q[0] = v.x * scale_s[ln * 4 + 0] + shift_s[ln * 4 + 0];
        q[1] = v.y * scale_s[ln * 4 + 1] + shift_s[ln * 4 + 1];
        q[2] = v.z * scale_s[ln * 4 + 2] + shift_s[ln * 4 + 2];
        q[3] = v.w * scale_s[ln * 4 + 3] + shift_s[ln * 4 + 3];
        float p[C_];
#pragma unroll
        for (int c = 0; c < C_; c++) p[c] = 0.f;
#pragma unroll
        for (int j = 0; j < 4; j++)
#pragma unroll
            for (int c = 0; c < C_; c++)
                p[c] += q[j] * wcr[j][c];
#pragma unroll
        for (int c = 0; c < C_; c++) {
#pragma unroll
            for (int off = 1; off < 64; off <<= 1)
                p[c] += __shfl_xor(p[c], off, 64);
        }
        if (ln == 0) {
#pragma unroll
            for (int c = 0; c < C_; c++)
                out[b * C_ + c] = p[c] + bc[c];
        }
    }
}

extern "C" void kernel_launch(void* const* d_in, const int* in_sizes, int n_in,
                              void* d_out, int out_size, void* d_ws, size_t ws_size,
                              hipStream_t stream) {
    const float* body   = (const float*)d_in[0];
    const float* hr     = (const float*)d_in[1];
    const float* hl     = (const float*)d_in[2];
    const int*   length = (const int*)  d_in[3];
    const float* W1     = (const float*)d_in[4];
    const float* b1     = (const float*)d_in[5];
    const float* gamma  = (const float*)d_in[6];
    const float* beta   = (const float*)d_in[7];
    const float* Wc     = (const float*)d_in[8];
    const float* bc     = (const float*)d_in[9];
    float* out = (float*)d_out;

    float*  pooled = (float*)d_ws;
    __bf16* W1bf   = (__bf16*)((char*)d_ws + 65536);

    hipMemsetAsync(d_ws, 0, 65536, stream);                    // pooled = 0 (relu >= 0)
    convert_w1<<<dim3(160), dim3(256), 0, stream>>>(W1, W1bf);
    fused_mlp_pool<<<dim3(64, B_), dim3(256), 0, stream>>>(body, hr, hl, length, b1, W1bf, pooled);
    bn_classifier<<<dim3(1), dim3(256), 0, stream>>>(pooled, gamma, beta, Wc, bc, out);
}

// Round 4
// 235.945 us; speedup vs baseline: 1.2656x; 1.0869x over previous
//
#include <hip/hip_runtime.h>
#include <hip/hip_bf16.h>

#define B_   64
#define T_   4096
#define K_   67
#define F_   134     // 2K input features
#define FP_  160     // padded to 5 K-tiles of 32
#define D_   256
#define C_   7
#define THR_ 0.1f
#define EPS_ 1e-5f

typedef __bf16 bf16x8 __attribute__((ext_vector_type(8)));
typedef float  f32x4  __attribute__((ext_vector_type(4)));

typedef __attribute__((address_space(1))) const unsigned int guint;
typedef __attribute__((address_space(3))) unsigned int luint;

// ws layout:
//   [0, 65536)            pooled  f32 [64][256]   (memset to 0 each launch)
//   [65536, 65536+81920)  W1bf    bf16 [256][160] (d-major, f contiguous, padded)

__device__ __forceinline__ int get_len(const int* L, int b) {
    // defensive: harness may store int64 (odd words zero since 1<=len<=4096)
    return (L[1] == 0) ? L[2 * b] : L[b];
}

// tiled transpose, both sides coalesced
__global__ void convert_w1(const float* __restrict__ W1, __bf16* __restrict__ W1bf) {
    __shared__ float tile[32][33];
    const int d0 = blockIdx.x * 32, f0 = blockIdx.y * 32;
    const int tx = threadIdx.x & 31, ty = threadIdx.x >> 5;   // ty 0..7
#pragma unroll
    for (int r = 0; r < 32; r += 8) {
        int f = f0 + ty + r;
        tile[ty + r][tx] = (f < F_) ? W1[f * D_ + d0 + tx] : 0.f;
    }
    __syncthreads();
#pragma unroll
    for (int r = 0; r < 32; r += 8) {
        int d = d0 + ty + r;
        W1bf[d * FP_ + f0 + tx] = (__bf16)tile[tx][ty + r];
    }
}

// One 32-timestep tile per block.
// Phase 1: async DMA raw slabs -> LDS (fire-and-forget, max MLP)
// Phase 2: LDS repack: gate by conf, fp32->bf16, MFMA-A layout (2 lanes/bank)
// Phase 3: MFMA 32t x 256d, K=160
__global__ __launch_bounds__(256, 3)
void fused_mlp_pool(const float* __restrict__ body,
                    const float* __restrict__ hr,
                    const float* __restrict__ hl,
                    const int*   __restrict__ length,
                    const float* __restrict__ b1,
                    const __bf16* __restrict__ W1bf,
                    float* __restrict__ pooled)
{
    const int b = blockIdx.y;
    const int len = get_len(length, b);
    const int t0 = blockIdx.x * 32;
    if (t0 >= len) return;

    __shared__ __align__(16) float  raw[6432];     // 25728 B: body|hr|hl slabs
    __shared__ __align__(16) __bf16 As[10 * 512];  // 10240 B: packed A tile

    const int tid  = threadIdx.x;
    const int wave = tid >> 6;
    const int lane = tid & 63;
    const int quad = lane >> 4;
    const int l16  = lane & 15;
    const int dbase = wave * 64;

    const long rowb = (long)b * T_;
    const float* bodyt = body + (rowb + t0) * 75;   // 9600 B, 16-aligned
    const float* hrt   = hr   + (rowb + t0) * 63;   // 8064 B, 16-aligned
    const float* hlt   = hl   + (rowb + t0) * 63;

    // ---- phase 1: async global->LDS DMA, 1024 B per wave-issue ----
    for (int i = wave; i < 9; i += 4)               // body: 9 full issues
        __builtin_amdgcn_global_load_lds(
            (guint*)(bodyt + i * 256 + lane * 4),
            (luint*)((char*)raw + i * 1024 + lane * 16), 16, 0, 0);
    for (int i = wave; i < 7; i += 4)               // hr: 7 full issues
        __builtin_amdgcn_global_load_lds(
            (guint*)(hrt + i * 256 + lane * 4),
            (luint*)((char*)raw + 9600 + i * 1024 + lane * 16), 16, 0, 0);
    for (int i = wave; i < 7; i += 4)               // hl: 7 full issues
        __builtin_amdgcn_global_load_lds(
            (guint*)(hlt + i * 256 + lane * 4),
            (luint*)((char*)raw + 17664 + i * 1024 + lane * 16), 16, 0, 0);

    // slab tails (384 + 896 + 896 B) as one float4 per thread
    if (tid < 136) {
        const float* g; int loff;                   // dword offsets
        if (tid < 24)      { g = bodyt + 2304 + tid * 4;        loff = 2304 + tid * 4; }
        else if (tid < 80) { g = hrt + 1792 + (tid - 24) * 4;   loff = 4192 + (tid - 24) * 4; }
        else               { g = hlt + 1792 + (tid - 80) * 4;   loff = 6208 + (tid - 80) * 4; }
        *(float4*)(raw + loff) = *(const float4*)g;
    }

    // B fragments (L2-hot W1bf), overlap with DMA
    bf16x8 bfrag[4][5];
    float  b1v[4];
#pragma unroll
    for (int n = 0; n < 4; n++) {
        int d = dbase + n * 16 + l16;
        const __bf16* p = W1bf + d * FP_ + quad * 8;
#pragma unroll
        for (int kt = 0; kt < 5; kt++)
            bfrag[n][kt] = *(const bf16x8*)(p + kt * 32);
        b1v[n] = b1[d];
    }

    // zero K-pad region: k-pairs 67..79, 32 t  (disjoint from phase-2 writes)
    for (int i = tid; i < 416; i += 256) {
        int t = i & 31, kp = 67 + (i >> 5);
        int w = ((t >> 4) * 5 + (kp >> 4)) * 256 + (((kp >> 2) & 3) * 16 + (t & 15)) * 4 + (kp & 3);
        ((unsigned int*)As)[w] = 0u;
    }
    __syncthreads();   // drains DMA (vmcnt) + tail/pad writes

    // ---- phase 2: repack. bit-sliced mapping -> packed writes 2 lanes/bank ----
#pragma unroll
    for (int it = 0; it < 8; it++) {
        int idx = it * 256 + tid;                       // 2048 = 32 t x 64 k
        int t = (((idx >> 5) & 3) << 3) | ((idx >> 2) & 7);
        int k = (((idx >> 7) & 15) << 2) | (idx & 3);
        int roff;
        if (k < 25)      roff = t * 75 + 3 * k;
        else if (k < 46) roff = 2400 + t * 63 + 3 * (k - 25);
        else             roff = 4416 + t * 63 + 3 * (k - 46);
        float x = raw[roff], y = raw[roff + 1], cf = raw[roff + 2];
        if (!(cf > THR_)) { x = 0.f; y = 0.f; }
        unsigned short ux = __builtin_bit_cast(unsigned short, (__bf16)x);
        unsigned short uy = __builtin_bit_cast(unsigned short, (__bf16)y);
        int w = ((t >> 4) * 5 + (k >> 4)) * 256 + (((k >> 2) & 3) * 16 + (t & 15)) * 4 + (k & 3);
        ((unsigned int*)As)[w] = (unsigned int)ux | ((unsigned int)uy << 16);
    }
    if (tid < 96) {                                     // cleanup k = 64..66
        int t = tid & 31, k = 64 + (tid >> 5);
        int roff = 4416 + t * 63 + 3 * (k - 46);
        float x = raw[roff], y = raw[roff + 1], cf = raw[roff + 2];
        if (!(cf > THR_)) { x = 0.f; y = 0.f; }
        unsigned short ux = __builtin_bit_cast(unsigned short, (__bf16)x);
        unsigned short uy = __builtin_bit_cast(unsigned short, (__bf16)y);
        int w = ((t >> 4) * 5 + (k >> 4)) * 256 + (((k >> 2) & 3) * 16 + (t & 15)) * 4 + (k & 3);
        ((unsigned int*)As)[w] = (unsigned int)ux | ((unsigned int)uy << 16);
    }
    __syncthreads();

    // ---- phase 3: MFMA 32t x 256d, K = 160 ----
    f32x4 acc[2][4];
#pragma unroll
    for (int m = 0; m < 2; m++)
#pragma unroll
        for (int n = 0; n < 4; n++)
            acc[m][n] = (f32x4){0.f, 0.f, 0.f, 0.f};

#pragma unroll
    for (int kt = 0; kt < 5; kt++) {
#pragma unroll
        for (int m = 0; m < 2; m++) {
            bf16x8 a = *(const bf16x8*)(As + (m * 5 + kt) * 512 + lane * 8);
#pragma unroll
            for (int n = 0; n < 4; n++)
                acc[m][n] = __builtin_amdgcn_mfma_f32_16x16x32_bf16(a, bfrag[n][kt], acc[m][n], 0, 0, 0);
        }
    }

    // ---- epilogue: bias + relu + validity + running max -> atomic ----
    float runmax[4] = {0.f, 0.f, 0.f, 0.f};
#pragma unroll
    for (int m = 0; m < 2; m++) {
        int trow0 = t0 + m * 16 + quad * 4;
#pragma unroll
        for (int r = 0; r < 4; r++) {
            bool valid = (trow0 + r) < len;
#pragma unroll
            for (int n = 0; n < 4; n++) {
                float v = acc[m][n][r] + b1v[n];
                v = (v > 0.f) ? v : 0.f;          // forces +0, never -0
                runmax[n] = (valid && v > runmax[n]) ? v : runmax[n];
            }
        }
    }
#pragma unroll
    for (int n = 0; n < 4; n++) {
        float r = runmax[n];
        r = fmaxf(r, __shfl_xor(r, 16, 64));
        r = fmaxf(r, __shfl_xor(r, 32, 64));
        if (quad == n) {
            atomicMax((unsigned int*)(pooled + b * D_ + dbase + n * 16 + l16),
                      __float_as_uint(r));        // all values >= +0
        }
    }
}

__global__ void bn_classifier(const float* __restrict__ pooled,
                              const float* __restrict__ gamma,
                              const float* __restrict__ beta,
                              const float* __restrict__ Wc,
                              const float* __restrict__ bc,
                              float* __restrict__ out)
{
    __shared__ float scale_s[D_], shift_s[D_];
    const int tid = threadIdx.x;   // == d for stats
    float s = 0.f, ss = 0.f;
#pragma unroll 8
    for (int b = 0; b < B_; b++) {
        float v = pooled[b * D_ + tid];   // coalesced
        s += v; ss += v * v;
    }
    float mean = s * (1.f / B_);
    float var  = ss * (1.f / B_) - mean * mean;
    var = fmaxf(var, 0.f);
    float sc = gamma[tid] * rsqrtf(var + EPS_);
    scale_s[tid] = sc;
    shift_s[tid] = beta[tid] - mean * sc;

    const int wv = tid >> 6, ln = tid & 63;
    float wcr[4][C_];
#pragma unroll
    for (int j = 0; j < 4; j++)
#pragma unroll
        for (int c = 0; c < C_; c++)
            wcr[j][c] = Wc[(ln * 4 + j) * C_ + c];
    __syncthreads();

    for (int b = wv * 16; b < wv * 16 + 16; b++) {
        float4 v = *(const float4*)(pooled + b * D_ + ln * 4);   // coalesced
        float q[4];
        q[0] = v.x * scale_s[ln * 4 + 0] + shift_s[ln * 4 + 0];
        q[1] = v.y * scale_s[ln * 4 + 1] + shift_s[ln * 4 + 1];
        q[2] = v.z * scale_s[ln * 4 + 2] + shift_s[ln * 4 + 2];
        q[3] = v.w * scale_s[ln * 4 + 3] + shift_s[ln * 4 + 3];
        float p[C_];
#pragma unroll
        for (int c = 0; c < C_; c++) p[c] = 0.f;
#pragma unroll
        for (int j = 0; j < 4; j++)
#pragma unroll
            for (int c = 0; c < C_; c++)
                p[c] += q[j] * wcr[j][c];
#pragma unroll
        for (int c = 0; c < C_; c++) {
#pragma unroll
            for (int off = 1; off < 64; off <<= 1)
                p[c] += __shfl_xor(p[c], off, 64);
        }
        if (ln == 0) {
#pragma unroll
            for (int c = 0; c < C_; c++)
                out[b * C_ + c] = p[c] + bc[c];
        }
    }
}

extern "C" void kernel_launch(void* const* d_in, const int* in_sizes, int n_in,
                              void* d_out, int out_size, void* d_ws, size_t ws_size,
                              hipStream_t stream) {
    const float* body   = (const float*)d_in[0];
    const float* hr     = (const float*)d_in[1];
    const float* hl     = (const float*)d_in[2];
    const int*   length = (const int*)  d_in[3];
    const float* W1     = (const float*)d_in[4];
    const float* b1     = (const float*)d_in[5];
    const float* gamma  = (const float*)d_in[6];
    const float* beta   = (const float*)d_in[7];
    const float* Wc     = (const float*)d_in[8];
    const float* bc     = (const float*)d_in[9];
    float* out = (float*)d_out;

    float*  pooled = (float*)d_ws;
    __bf16* W1bf   = (__bf16*)((char*)d_ws + 65536);

    hipMemsetAsync(d_ws, 0, 65536, stream);                    // pooled = 0 (relu >= 0)
    convert_w1<<<dim3(8, 5), dim3(256), 0, stream>>>(W1, W1bf);
    fused_mlp_pool<<<dim3(128, B_), dim3(256), 0, stream>>>(body, hr, hl, length, b1, W1bf, pooled);
    bn_classifier<<<dim3(1), dim3(256), 0, stream>>>(pooled, gamma, beta, Wc, bc, out);
}